// Round 2
// 128.580 us; speedup vs baseline: 1.0064x; 1.0064x over previous
//
#include <hip/hip_runtime.h>
#include <stdint.h>

#define BB 64
#define LL 512
#define DD 300
#define CC 128

// ws layout (floats):
//   Gpart : [64][32][3][300] = 1,843,200  (non-atomic per-half-block partials)
//   (hole): [64][900]        =    57,600  (old Gred slot, unused now)
//   W2    : [128][900]       =   115,200  (fused sim∘fc weights)
//   bias2 : [128]
#define OFF_GRED  (BB * 32 * 3 * DD)
#define OFF_W2    (OFF_GRED + BB * 3 * DD)
#define OFF_BIAS2 (OFF_W2 + CC * 3 * DD)

// ---------------------------------------------------------------------------
// Kernel 1: gather + (independent) head-weight precompute, one grid.
// Blocks 0..1023   : R7's best gather — 8-deep batched row loads.
//   Gpart[b][p][kk][d] = sum_{t in half-block p} u_k[t] * embed[x[b,t]][d]
// Blocks 1024..1503: W2[c][kk*300+d] = sum_cp fcw[c,kk*128+cp]*conv_w[cp,d]
// Blocks 1504..1535: bias2[c] = sum_j fcw[c,j]*(cb[j&127]*Sk+bk) + fcb[c]
// (identical to the 129.1 µs verified version)
// ---------------------------------------------------------------------------
__global__ __launch_bounds__(256) void k_gather(
    const int* __restrict__ x, const float* __restrict__ embed,
    const float* __restrict__ conv_w, const float* __restrict__ conv_b,
    const float* __restrict__ w3, const float* __restrict__ b3,
    const float* __restrict__ w4, const float* __restrict__ b4,
    const float* __restrict__ w5, const float* __restrict__ b5,
    const float* __restrict__ fcw, const float* __restrict__ fcb,
    float* __restrict__ Gpart, float* __restrict__ W2,
    float* __restrict__ bias2) {
  const int blk = blockIdx.x;
  const int tid = threadIdx.x;

  if (blk < 1024) {  // ---------------- gather ----------------
    const int b = blk >> 4;
    const int tc = blk & 15;
    const int sub = tid >> 7;    // half-block: 16 tokens each
    const int stid = tid & 127;  // float2 slot

    __shared__ int sx[32];
    __shared__ float su[3][32];

    if (tid < 32) {
      const int t = tc * 32 + tid;
      sx[tid] = x[b * LL + t];
      const float* ws[3] = {w3, w4, w5};
#pragma unroll
      for (int kk = 0; kk < 3; ++kk) {
        const int k = kk + 3;
        int lo = t - k + 1; if (lo < 0) lo = 0;
        int hi = t; const int lim = LL - k - 1; if (hi > lim) hi = lim;
        float s = 0.f;
        for (int l = lo; l <= hi; ++l) s += ws[kk][l];
        su[kk][tid] = s;
      }
    }
    __syncthreads();

    float a0x = 0.f, a0y = 0.f, a1x = 0.f, a1y = 0.f, a2x = 0.f, a2y = 0.f;
    float c0x = 0.f, c0y = 0.f, c1x = 0.f, c1y = 0.f, c2x = 0.f, c2y = 0.f;
    const bool tail = stid < (DD / 2 - 128);  // slots 128..149 -> 22 lanes

#pragma unroll
    for (int half = 0; half < 2; ++half) {
      const int base = sub * 16 + half * 8;
      float2 v[8], u[8];
#pragma unroll
      for (int i = 0; i < 8; ++i) {
        const float2* rp = (const float2*)(embed + (size_t)sx[base + i] * DD);
        v[i] = rp[stid];
      }
      if (tail) {
#pragma unroll
        for (int i = 0; i < 8; ++i) {
          const float2* rp =
              (const float2*)(embed + (size_t)sx[base + i] * DD);
          u[i] = rp[128 + stid];
        }
      }
#pragma unroll
      for (int i = 0; i < 8; ++i) {
        const int j = base + i;
        const float w0 = su[0][j], w1 = su[1][j], w2 = su[2][j];
        a0x += w0 * v[i].x; a0y += w0 * v[i].y;
        a1x += w1 * v[i].x; a1y += w1 * v[i].y;
        a2x += w2 * v[i].x; a2y += w2 * v[i].y;
        if (tail) {
          c0x += w0 * u[i].x; c0y += w0 * u[i].y;
          c1x += w1 * u[i].x; c1y += w1 * u[i].y;
          c2x += w2 * u[i].x; c2y += w2 * u[i].y;
        }
      }
    }

    const int p = tc * 2 + sub;  // 0..31
    float* Gp = Gpart + (size_t)(b * 32 + p) * (3 * DD);
    const int d0 = 2 * stid;
    Gp[0 * DD + d0] = a0x; Gp[0 * DD + d0 + 1] = a0y;
    Gp[1 * DD + d0] = a1x; Gp[1 * DD + d0 + 1] = a1y;
    Gp[2 * DD + d0] = a2x; Gp[2 * DD + d0 + 1] = a2y;
    if (tail) {
      const int d1 = 2 * (128 + stid);
      Gp[0 * DD + d1] = c0x; Gp[0 * DD + d1 + 1] = c0y;
      Gp[1 * DD + d1] = c1x; Gp[1 * DD + d1 + 1] = c1y;
      Gp[2 * DD + d1] = c2x; Gp[2 * DD + d1 + 1] = c2y;
    }
  } else if (blk < 1504) {  // ---------------- W2 precompute ----------------
    const int w = (blk - 1024) * 4 + (tid >> 6);  // 0..1919
    const int lane = tid & 63;
    const int c = w / 15;
    const int rem = w - c * 15;
    const int kk = rem / 5;
    const int chunk = rem - kk * 5;
    const int d = chunk * 64 + lane;
    if (d < DD) {
      const float* fr = fcw + c * (3 * CC) + kk * CC;  // 128 wave-uniform
      float acc0 = 0.f, acc1 = 0.f;
#pragma unroll 4
      for (int cp = 0; cp < CC; cp += 2) {
        acc0 += fr[cp] * conv_w[cp * DD + d];
        acc1 += fr[cp + 1] * conv_w[(cp + 1) * DD + d];
      }
      W2[c * (3 * DD) + kk * DD + d] = acc0 + acc1;
    }
  } else {  // ---------------- bias2 ----------------
    const int wid = tid >> 6;
    const int lane = tid & 63;
    const int c = (blk - 1504) * 4 + wid;  // 0..127
    float sk[3];
    const float* ws[3] = {w3, w4, w5};
#pragma unroll
    for (int kk = 0; kk < 3; ++kk) {
      const int len = LL - (kk + 3);
      float s = 0.f;
      for (int l = lane; l < len; l += 64) s += ws[kk][l];
#pragma unroll
      for (int off = 32; off >= 1; off >>= 1) s += __shfl_down(s, off, 64);
      sk[kk] = __shfl(s, 0, 64);
    }
    const float bkv[3] = {b3[0], b4[0], b5[0]};
    float acc = 0.f;
#pragma unroll
    for (int s6 = 0; s6 < 6; ++s6) {
      const int j = s6 * 64 + lane;
      const int kk = j >> 7;
      const int cp = j & 127;
      acc += fcw[c * (3 * CC) + j] * (conv_b[cp] * sk[kk] + bkv[kk]);
    }
#pragma unroll
    for (int off = 32; off >= 1; off >>= 1) acc += __shfl_down(acc, off, 64);
    if (lane == 0) bias2[c] = acc + fcb[c];
  }
}

// ---------------------------------------------------------------------------
// Kernel 2: fused reduce + head GEMV — replaces old k_reduce + k_out.
// 256 blocks (1/CU) x 256 threads. Block (b, cgrp = blk&3):
//   1) reduce Gpart[b][0..31][900] -> LDS gred[900]
//      (225 threads x 32 coalesced float4 loads; same pattern as old
//       k_reduce, 4 blocks share b -> Gpart slice is L2-hot on re-reads)
//   2) GEMV 32 channels (cgrp*32..+31), 8 per wave as 4 sequential pairs:
//      out[b,c] = <W2[c,:], gred> + bias2[c]
// Removes one device-wide drain+launch boundary and the Gred global
// round-trip (230 KB write + read).
// ---------------------------------------------------------------------------
__global__ __launch_bounds__(256) void k_redout(
    const float* __restrict__ Gpart, const float* __restrict__ W2,
    const float* __restrict__ bias2, float* __restrict__ out) {
  const int b = blockIdx.x >> 2;     // 0..63
  const int cgrp = blockIdx.x & 3;   // channel group of 32
  const int tid = threadIdx.x;
  __shared__ float gred[3 * DD];     // 900 floats = 225 float4

  if (tid < 225) {
    const float4* gp = (const float4*)Gpart + (size_t)b * 32 * 225 + tid;
    float4 s = gp[0];
#pragma unroll
    for (int p = 1; p < 32; ++p) {
      const float4 v = gp[(size_t)p * 225];
      s.x += v.x; s.y += v.y; s.z += v.z; s.w += v.w;
    }
    ((float4*)gred)[tid] = s;
  }
  __syncthreads();

  const int w = tid >> 6;
  const int lane = tid & 63;
  const float2* gr = (const float2*)gred;  // 450 float2
#pragma unroll
  for (int pair = 0; pair < 4; ++pair) {
    const int c0 = cgrp * 32 + w * 8 + pair * 2;
    const float2* wr0 = (const float2*)(W2 + c0 * (3 * DD));
    const float2* wr1 = (const float2*)(W2 + (c0 + 1) * (3 * DD));
    float a0 = 0.f, a1 = 0.f;
#pragma unroll
    for (int s = 0; s < 7; ++s) {
      const float2 g = gr[s * 64 + lane];
      const float2 va = wr0[s * 64 + lane];
      const float2 vb = wr1[s * 64 + lane];
      a0 += va.x * g.x + va.y * g.y;
      a1 += vb.x * g.x + vb.y * g.y;
    }
    if (lane < 2) {
      const float2 g = gr[448 + lane];
      const float2 va = wr0[448 + lane];
      const float2 vb = wr1[448 + lane];
      a0 += va.x * g.x + va.y * g.y;
      a1 += vb.x * g.x + vb.y * g.y;
    }
#pragma unroll
    for (int off = 32; off >= 1; off >>= 1) {
      a0 += __shfl_down(a0, off, 64);
      a1 += __shfl_down(a1, off, 64);
    }
    if (lane == 0) {
      out[b * CC + c0] = a0 + bias2[c0];
      out[b * CC + c0 + 1] = a1 + bias2[c0 + 1];
    }
  }
}

// ---------------------------------------------------------------------------
extern "C" void kernel_launch(void* const* d_in, const int* in_sizes, int n_in,
                              void* d_out, int out_size, void* d_ws,
                              size_t ws_size, hipStream_t stream) {
  const int* x = (const int*)d_in[0];
  const float* embed = (const float*)d_in[1];
  const float* conv_w = (const float*)d_in[2];
  const float* conv_b = (const float*)d_in[3];
  const float* fc3w = (const float*)d_in[4];
  const float* fc3b = (const float*)d_in[5];
  const float* fc4w = (const float*)d_in[6];
  const float* fc4b = (const float*)d_in[7];
  const float* fc5w = (const float*)d_in[8];
  const float* fc5b = (const float*)d_in[9];
  const float* fcw = (const float*)d_in[10];
  const float* fcb = (const float*)d_in[11];

  float* Gpart = (float*)d_ws;
  float* W2 = (float*)d_ws + OFF_W2;
  float* bias2 = (float*)d_ws + OFF_BIAS2;

  k_gather<<<dim3(1536), dim3(256), 0, stream>>>(
      x, embed, conv_w, conv_b, fc3w, fc3b, fc4w, fc4b, fc5w, fc5b, fcw, fcb,
      Gpart, W2, bias2);
  k_redout<<<dim3(256), dim3(256), 0, stream>>>(Gpart, W2, bias2,
                                                (float*)d_out);
}